// Round 9
// baseline (829.810 us; speedup 1.0000x reference)
//
#include <hip/hip_runtime.h>
#include <cmath>

// Problem constants (fixed by reference): B=8, N=2048, eps=0.01, 50 iters.
#define BATCH 8
#define NPT   2048
#define NPAIR (NPT / 2)               // 1024 column pairs
#define NPTS  (BATCH * NPT)
#define TILES 64                      // blocks per batch-pair (32 rows each)
#define GRID_MAIN 256                 // 1 block/CU; block owns batches (b0, b0+4)
#define THREADS 1024                  // 16 waves -> 4/SIMD
#define ITERS 50

// exp(v_j - 100*cost) = exp2( C_LOG2E*v_j + NEG100C*(n_i + n_j) + S200C*dot )
#define C_LOG2E 1.4426950408889634f
#define NEG100C (-144.26950408889634f)   // -100 * log2(e)
#define S200C   288.53900817779268f      //  200 * log2(e)
#define EPS_LOG 1e-8f
#define LN2_01  0.006931471805599453f    // 0.01 * ln(2)

typedef float v2f __attribute__((ext_vector_type(2)));
typedef float v4f __attribute__((ext_vector_type(4)));
typedef unsigned long long u64t;

static __device__ __forceinline__ float fast_exp2(float x) {
#if __has_builtin(__builtin_amdgcn_exp2f)
    return __builtin_amdgcn_exp2f(x);
#else
    return exp2f(x);
#endif
}

// Guaranteed-packed fp32 ops (VOP3P); pure register asm, schedulable.
static __device__ __forceinline__ v2f pk_fma(v2f a, v2f b, v2f c) {
    v2f d;
    asm("v_pk_fma_f32 %0, %1, %2, %3" : "=v"(d) : "v"(a), "v"(b), "v"(c));
    return d;
}
static __device__ __forceinline__ v2f pk_add(v2f a, v2f b) {
    v2f d;
    asm("v_pk_add_f32 %0, %1, %2" : "=v"(d) : "v"(a), "v"(b));
    return d;
}

// Coherence-point (agent-scope, relaxed) accessors for cross-block data.
static __device__ __forceinline__ float gload(const float* p) {
    return __hip_atomic_load(p, __ATOMIC_RELAXED, __HIP_MEMORY_SCOPE_AGENT);
}
static __device__ __forceinline__ void gstore(float* p, float val) {
    __hip_atomic_store(p, val, __ATOMIC_RELAXED, __HIP_MEMORY_SCOPE_AGENT);
}
static __device__ __forceinline__ u64t gload2(const float* p) {   // 2 floats
    return __hip_atomic_load((const u64t*)p, __ATOMIC_RELAXED,
                             __HIP_MEMORY_SCOPE_AGENT);
}

// ---------------------------------------------------------------------------
__global__ void init_kernel(float* __restrict__ out,
                            unsigned int* __restrict__ flags) {
    int t = threadIdx.x;          // 512 threads
    if (t < BATCH) out[t] = 0.0f;
    flags[t] = 0u;                // BATCH*TILES = 512 flags
}

// ---------------------------------------------------------------------------
// Split flag barrier (R7/R8-proven machinery).
// arrive: syncthreads drains all block stores (sc1 -> coherence point),
//         then thread0 stores the phase number to this block's flag.
// wait:   wave0's 64 lanes poll the batch's 64 flags; block-sync after.
// ---------------------------------------------------------------------------
static __device__ __forceinline__ void bar_arrive(unsigned int* flags,
                                                  int slot, unsigned int ph) {
    __syncthreads();
    if (threadIdx.x == 0)
        __hip_atomic_store(&flags[slot], ph, __ATOMIC_RELAXED,
                           __HIP_MEMORY_SCOPE_AGENT);
}
static __device__ __forceinline__ void bar_wait(const unsigned int* bflags,
                                                int wave, int lane,
                                                unsigned int ph) {
    if (wave == 0) {
        while (__hip_atomic_load(&bflags[lane], __ATOMIC_RELAXED,
                                 __HIP_MEMORY_SCOPE_AGENT) < ph) {
            __builtin_amdgcn_s_sleep(1);
        }
    }
    __syncthreads();
    __builtin_amdgcn_sched_barrier(0);
}

// ---------------------------------------------------------------------------
// Row-per-lane half-pass core: lane owns ONE row (splatted constants);
// columns stream as (half-wave-)uniform b128 reads (broadcast).
// 16 waves x 2 halves cover the 1024 pairs; each lane sums 32 pairs.
// ---------------------------------------------------------------------------
static __device__ __forceinline__ float half_core(
        const v4f* cdXY, const v4f* cdZW, int p0,
        v2f RX, v2f RY, v2f RZ, v2f RC)
{
    float accx = 0.0f, accy = 0.0f;
#pragma unroll 4
    for (int s = 0; s < 32; s++) {
        v4f a  = cdXY[p0 + s];                      // uniform ds_read_b128
        v4f bz = cdZW[p0 + s];                      // uniform ds_read_b128
        v2f xx = __builtin_shufflevector(a,  a,  0, 1);
        v2f yy = __builtin_shufflevector(a,  a,  2, 3);
        v2f zz = __builtin_shufflevector(bz, bz, 0, 1);
        v2f ww = __builtin_shufflevector(bz, bz, 2, 3);
        v2f t = pk_fma(xx, RX, ww);
        t = pk_fma(yy, RY, t);
        t = pk_fma(zz, RZ, t);
        t = pk_add(t, RC);
        accx += fast_exp2(t.x);
        accy += fast_exp2(t.y);
    }
    return accx + accy;
}

// ---------------------------------------------------------------------------
// Dual-batch + row-per-lane persistent kernel.
// Batch B's half-pass compute covers batch A's barrier propagation; folds'
// coherent loads for A and B overlap each other.
// LDS = 128 KB tiles + 2.2 KB reduce pad; 1 block/CU, 4 waves/SIMD.
// ---------------------------------------------------------------------------
__global__ __launch_bounds__(THREADS, 4) void sinkhorn_kernel(
        const float* __restrict__ x1, const float* __restrict__ x2,
        float* __restrict__ u, float* __restrict__ v,
        unsigned int* __restrict__ flags, float* __restrict__ out)
{
    __shared__ v4f c1XY[2][NPAIR], c1ZW[2][NPAIR];   // side-1 (dual = u)
    __shared__ v4f c2XY[2][NPAIR], c2ZW[2][NPAIR];   // side-2 (dual = v)
    __shared__ float part[32][17];                   // padded cross-wave reduce

    const int b0   = blockIdx.x / TILES;      // 0..3
    const int tile = blockIdx.x % TILES;
    const int bA = b0, bB = b0 + 4;
    const int baseA = bA * NPT, baseB = bB * NPT;
    const int slotA = bA * TILES + tile, slotB = bB * TILES + tile;
    const unsigned int* flA = flags + bA * TILES;
    const unsigned int* flB = flags + bB * TILES;

    const int tid  = threadIdx.x;
    const int wave = tid >> 6;
    const int lane = tid & 63;
    const int rloc = lane & 31;              // local row 0..31
    const int ch   = lane >> 5;              // column half of this wave's span
    const int row  = tile * 32 + rloc;       // global row in batch
    const int p0   = wave * 64 + ch * 32;    // this lane's pair base

    const float log_mu = logf(1.0f / (float)NPT + EPS_LOG);

    // ---- one-time staging: thread t stages pair t, both batches/sides ----
    float P1a[2], P1b[2], P2a[2], P2b[2];
#pragma unroll
    for (int g = 0; g < 2; g++) {
        int base = g ? baseB : baseA;
        const float* p = x1 + 3 * (base + 2 * tid);
        float ax = p[0], ay = p[1], az = p[2];
        float bx = p[3], by = p[4], bz = p[5];
        float na = fmaf(ax, ax, fmaf(ay, ay, az * az));
        float nb = fmaf(bx, bx, fmaf(by, by, bz * bz));
        P1a[g] = na * NEG100C;  P1b[g] = nb * NEG100C;
        c1XY[g][tid] = (v4f){ax * S200C, bx * S200C, ay * S200C, by * S200C};
        c1ZW[g][tid] = (v4f){az * S200C, bz * S200C, P1a[g], P1b[g]};

        p = x2 + 3 * (base + 2 * tid);
        ax = p[0]; ay = p[1]; az = p[2];
        bx = p[3]; by = p[4]; bz = p[5];
        na = fmaf(ax, ax, fmaf(ay, ay, az * az));
        nb = fmaf(bx, bx, fmaf(by, by, bz * bz));
        P2a[g] = na * NEG100C;  P2b[g] = nb * NEG100C;
        c2XY[g][tid] = (v4f){ax * S200C, bx * S200C, ay * S200C, by * S200C};
        c2ZW[g][tid] = (v4f){az * S200C, bz * S200C, P2a[g], P2b[g]};
    }

    // ---- lane's single-row constants (splatted), both sides/batches ----
    v2f RX1[2], RY1[2], RZ1[2], RC1[2], RX2[2], RY2[2], RZ2[2], RC2[2];
    float rc1s[2];
#pragma unroll
    for (int g = 0; g < 2; g++) {
        int base = g ? baseB : baseA;
        const float* p = x1 + 3 * (base + row);
        float a = p[0], bb = p[1], c = p[2];
        float nn = NEG100C * fmaf(a, a, fmaf(bb, bb, c * c));
        RX1[g] = (v2f){a, a};  RY1[g] = (v2f){bb, bb};
        RZ1[g] = (v2f){c, c};  RC1[g] = (v2f){nn, nn};
        rc1s[g] = nn;
        p = x2 + 3 * (base + row);
        a = p[0]; bb = p[1]; c = p[2];
        nn = NEG100C * fmaf(a, a, fmaf(bb, bb, c * c));
        RX2[g] = (v2f){a, a};  RY2[g] = (v2f){bb, bb};
        RZ2[g] = (v2f){c, c};  RC2[g] = (v2f){nn, nn};
    }
    __syncthreads();

    // ---- 50 Sinkhorn iterations; B-compute hides A-barrier latency ----
    unsigned int ph = 0;
    for (int it = 0; it < ITERS; it++) {
        if (it > 0) {   // fold fresh v into side-2 w-slots (A/B loads overlap)
            u64t dA = gload2(v + baseA + 2 * tid);
            u64t dB = gload2(v + baseB + 2 * tid);
            reinterpret_cast<v2f*>(&c2ZW[0][tid])[1] = (v2f){
                fmaf(C_LOG2E, __uint_as_float((unsigned)dA), P2a[0]),
                fmaf(C_LOG2E, __uint_as_float((unsigned)(dA >> 32)), P2b[0])};
            reinterpret_cast<v2f*>(&c2ZW[1][tid])[1] = (v2f){
                fmaf(C_LOG2E, __uint_as_float((unsigned)dB), P2a[1]),
                fmaf(C_LOG2E, __uint_as_float((unsigned)(dB >> 32)), P2b[1])};
            __syncthreads();
        }
        // --- u half, batch A ---
        {
            float s = half_core(c2XY[0], c2ZW[0], p0,
                                RX1[0], RY1[0], RZ1[0], RC1[0]);
            s += __shfl_xor(s, 32, 64);
            if (lane < 32) part[rloc][wave] = s;
            __syncthreads();
            if (wave == 0) {
                float t = 0.0f;
#pragma unroll
                for (int w = 0; w < 16; w++) t += part[rloc][w];
                float res = log_mu - __logf(t + EPS_LOG);
                if (lane < 32) gstore(&u[baseA + row], res);   // coalesced
            }
        }
        bar_arrive(flags, slotA, ph + 1);
        // --- u half, batch B (covers A's barrier propagation) ---
        {
            float s = half_core(c2XY[1], c2ZW[1], p0,
                                RX1[1], RY1[1], RZ1[1], RC1[1]);
            s += __shfl_xor(s, 32, 64);
            if (lane < 32) part[rloc][wave] = s;
            __syncthreads();
            if (wave == 0) {
                float t = 0.0f;
#pragma unroll
                for (int w = 0; w < 16; w++) t += part[rloc][w];
                float res = log_mu - __logf(t + EPS_LOG);
                if (lane < 32) gstore(&u[baseB + row], res);
            }
        }
        bar_arrive(flags, slotB, ph + 1);
        bar_wait(flA, wave, lane, ph + 1);
        bar_wait(flB, wave, lane, ph + 1);
        {   // fold fresh u into side-1 w-slots (A/B loads overlap)
            u64t dA = gload2(u + baseA + 2 * tid);
            u64t dB = gload2(u + baseB + 2 * tid);
            reinterpret_cast<v2f*>(&c1ZW[0][tid])[1] = (v2f){
                fmaf(C_LOG2E, __uint_as_float((unsigned)dA), P1a[0]),
                fmaf(C_LOG2E, __uint_as_float((unsigned)(dA >> 32)), P1b[0])};
            reinterpret_cast<v2f*>(&c1ZW[1][tid])[1] = (v2f){
                fmaf(C_LOG2E, __uint_as_float((unsigned)dB), P1a[1]),
                fmaf(C_LOG2E, __uint_as_float((unsigned)(dB >> 32)), P1b[1])};
            __syncthreads();
        }
        // --- v half, batch A ---
        {
            float s = half_core(c1XY[0], c1ZW[0], p0,
                                RX2[0], RY2[0], RZ2[0], RC2[0]);
            s += __shfl_xor(s, 32, 64);
            if (lane < 32) part[rloc][wave] = s;
            __syncthreads();
            if (wave == 0) {
                float t = 0.0f;
#pragma unroll
                for (int w = 0; w < 16; w++) t += part[rloc][w];
                float res = log_mu - __logf(t + EPS_LOG);
                if (lane < 32) gstore(&v[baseA + row], res);
            }
        }
        bar_arrive(flags, slotA, ph + 2);
        // --- v half, batch B ---
        {
            float s = half_core(c1XY[1], c1ZW[1], p0,
                                RX2[1], RY2[1], RZ2[1], RC2[1]);
            s += __shfl_xor(s, 32, 64);
            if (lane < 32) part[rloc][wave] = s;
            __syncthreads();
            if (wave == 0) {
                float t = 0.0f;
#pragma unroll
                for (int w = 0; w < 16; w++) t += part[rloc][w];
                float res = log_mu - __logf(t + EPS_LOG);
                if (lane < 32) gstore(&v[baseB + row], res);
            }
        }
        bar_arrive(flags, slotB, ph + 2);
        bar_wait(flA, wave, lane, ph + 2);
        bar_wait(flB, wave, lane, ph + 2);
        ph += 2;
    }

    // ---- fused EMD epilogue (both batches):
    //      cost = 0.01*(u_i+v_j) - 0.01*ln2 * t  (algebraically exact) ----
    v2f* cvp0 = reinterpret_cast<v2f*>(c1XY[0]);   // reused, no other reader
    v2f* cvp1 = reinterpret_cast<v2f*>(c1XY[1]);
    {
        u64t dA = gload2(v + baseA + 2 * tid);
        u64t dB = gload2(v + baseB + 2 * tid);
        float aA = __uint_as_float((unsigned)dA);
        float bA2 = __uint_as_float((unsigned)(dA >> 32));
        float aB = __uint_as_float((unsigned)dB);
        float bB2 = __uint_as_float((unsigned)(dB >> 32));
        reinterpret_cast<v2f*>(&c2ZW[0][tid])[1] =
            (v2f){fmaf(C_LOG2E, aA, P2a[0]), fmaf(C_LOG2E, bA2, P2b[0])};
        reinterpret_cast<v2f*>(&c2ZW[1][tid])[1] =
            (v2f){fmaf(C_LOG2E, aB, P2a[1]), fmaf(C_LOG2E, bB2, P2b[1])};
        cvp0[tid] = (v2f){0.01f * aA, 0.01f * bA2};
        cvp1[tid] = (v2f){0.01f * aB, 0.01f * bB2};
    }
    __syncthreads();

    const v2f NL2 = {-LN2_01, -LN2_01};
    float es[2];
#pragma unroll
    for (int g = 0; g < 2; g++) {
        int base = g ? baseB : baseA;
        v2f* cvp = g ? cvp1 : cvp0;
        float ur = gload(&u[base + row]);
        float rcs = fmaf(C_LOG2E, ur, rc1s[g]);
        v2f RCC = (v2f){rcs, rcs};
        float sus = 0.01f * ur;
        v2f SU = (v2f){sus, sus};
        v2f eacc = {0.0f, 0.0f};
#pragma unroll 4
        for (int s = 0; s < 32; s++) {
            v4f a   = c2XY[g][p0 + s];
            v4f bz  = c2ZW[g][p0 + s];
            v2f cv2 = cvp[p0 + s];
            v2f xx = __builtin_shufflevector(a,  a,  0, 1);
            v2f yy = __builtin_shufflevector(a,  a,  2, 3);
            v2f zz = __builtin_shufflevector(bz, bz, 0, 1);
            v2f ww = __builtin_shufflevector(bz, bz, 2, 3);
            v2f t = pk_fma(xx, RX1[g], ww);
            t = pk_fma(yy, RY1[g], t);
            t = pk_fma(zz, RZ1[g], t);
            t = pk_add(t, RCC);
            v2f c2 = pk_fma(t, NL2, pk_add(SU, cv2));
            eacc.x = fmaf(fast_exp2(t.x), c2.x, eacc.x);
            eacc.y = fmaf(fast_exp2(t.y), c2.y, eacc.y);
        }
        float e = eacc.x + eacc.y;
#pragma unroll
        for (int m = 32; m >= 1; m >>= 1) e += __shfl_xor(e, m, 64);
        es[g] = e;
    }

    if (lane == 0) { part[0][wave] = es[0]; part[1][wave] = es[1]; }
    __syncthreads();
    if (tid == 0) {
        float sA = 0.0f, sB = 0.0f;
#pragma unroll
        for (int w = 0; w < 16; w++) { sA += part[0][w]; sB += part[1][w]; }
        atomicAdd(&out[bA], sA);
        atomicAdd(&out[bB], sB);
    }
}

// ---------------------------------------------------------------------------
extern "C" void kernel_launch(void* const* d_in, const int* in_sizes, int n_in,
                              void* d_out, int out_size, void* d_ws, size_t ws_size,
                              hipStream_t stream) {
    (void)in_sizes; (void)n_in; (void)out_size; (void)ws_size;
    const float* x1 = (const float*)d_in[0];
    const float* x2 = (const float*)d_in[1];
    float* out = (float*)d_out;

    char* ws = (char*)d_ws;
    float* u = (float*)ws;                             // NPTS floats
    float* v = u + NPTS;                               // NPTS floats
    unsigned int* flags = (unsigned int*)(v + NPTS);   // BATCH*TILES uints

    init_kernel<<<1, 512, 0, stream>>>(out, flags);
    sinkhorn_kernel<<<GRID_MAIN, THREADS, 0, stream>>>(x1, x2, u, v, flags, out);
}

// Round 10
// 825.294 us; speedup vs baseline: 1.0055x; 1.0055x over previous
//
#include <hip/hip_runtime.h>
#include <cmath>

// Problem constants (fixed by reference): B=8, N=2048, eps=0.01, 50 iters.
#define BATCH 8
#define NPT   2048
#define NPAIR (NPT / 2)               // 1024 column pairs
#define NPTS  (BATCH * NPT)
#define TILES 64                      // blocks per batch-pair (32 rows each)
#define GRID_MAIN 256                 // 1 block/CU; block owns batches (b0, b0+4)
#define THREADS 1024                  // 16 waves -> 4/SIMD
#define ITERS 50

// exp(v_j - 100*cost) = exp2( C_LOG2E*v_j + NEG100C*(n_i + n_j) + S200C*dot )
#define C_LOG2E 1.4426950408889634f
#define NEG100C (-144.26950408889634f)   // -100 * log2(e)
#define S200C   288.53900817779268f      //  200 * log2(e)
#define EPS_LOG 1e-8f
#define LN2_01  0.006931471805599453f    // 0.01 * ln(2)

typedef float v2f __attribute__((ext_vector_type(2)));
typedef float v4f __attribute__((ext_vector_type(4)));
typedef unsigned long long u64t;

static __device__ __forceinline__ float fast_exp2(float x) {
#if __has_builtin(__builtin_amdgcn_exp2f)
    return __builtin_amdgcn_exp2f(x);
#else
    return exp2f(x);
#endif
}

// Guaranteed-packed fp32 ops (VOP3P); pure register asm, schedulable.
static __device__ __forceinline__ v2f pk_fma(v2f a, v2f b, v2f c) {
    v2f d;
    asm("v_pk_fma_f32 %0, %1, %2, %3" : "=v"(d) : "v"(a), "v"(b), "v"(c));
    return d;
}
static __device__ __forceinline__ v2f pk_add(v2f a, v2f b) {
    v2f d;
    asm("v_pk_add_f32 %0, %1, %2" : "=v"(d) : "v"(a), "v"(b));
    return d;
}

// Coherence-point (agent-scope, relaxed) accessors for cross-block data.
static __device__ __forceinline__ float gload(const float* p) {
    return __hip_atomic_load(p, __ATOMIC_RELAXED, __HIP_MEMORY_SCOPE_AGENT);
}
static __device__ __forceinline__ void gstore(float* p, float val) {
    __hip_atomic_store(p, val, __ATOMIC_RELAXED, __HIP_MEMORY_SCOPE_AGENT);
}
static __device__ __forceinline__ u64t gload2(const float* p) {   // 2 floats
    return __hip_atomic_load((const u64t*)p, __ATOMIC_RELAXED,
                             __HIP_MEMORY_SCOPE_AGENT);
}

// ---------------------------------------------------------------------------
__global__ void init_kernel(float* __restrict__ out,
                            unsigned int* __restrict__ flags) {
    int t = threadIdx.x;          // 512 threads
    if (t < BATCH) out[t] = 0.0f;
    flags[t] = 0u;                // BATCH*TILES = 512 flags
}

// ---------------------------------------------------------------------------
// Split flag barrier (R7-R9 proven machinery).
// ---------------------------------------------------------------------------
static __device__ __forceinline__ void bar_arrive(unsigned int* flags,
                                                  int slot, unsigned int ph) {
    __syncthreads();
    if (threadIdx.x == 0)
        __hip_atomic_store(&flags[slot], ph, __ATOMIC_RELAXED,
                           __HIP_MEMORY_SCOPE_AGENT);
}
static __device__ __forceinline__ void bar_wait(const unsigned int* bflags,
                                                int wave, int lane,
                                                unsigned int ph) {
    if (wave == 0) {
        while (__hip_atomic_load(&bflags[lane], __ATOMIC_RELAXED,
                                 __HIP_MEMORY_SCOPE_AGENT) < ph) {
            __builtin_amdgcn_s_sleep(1);
        }
    }
    __syncthreads();
    __builtin_amdgcn_sched_barrier(0);
}

// ---------------------------------------------------------------------------
// Row-per-lane half-pass core: lane owns ONE row (splatted constants);
// columns stream as (half-wave-)uniform b128 reads (broadcast).
// 16 waves x 2 halves cover the 1024 pairs; each lane sums 32 pairs.
// ---------------------------------------------------------------------------
static __device__ __forceinline__ float half_core(
        const v4f* cdXY, const v4f* cdZW, int p0,
        v2f RX, v2f RY, v2f RZ, v2f RC)
{
    float accx = 0.0f, accy = 0.0f;
#pragma unroll 4
    for (int s = 0; s < 32; s++) {
        v4f a  = cdXY[p0 + s];                      // uniform ds_read_b128
        v4f bz = cdZW[p0 + s];                      // uniform ds_read_b128
        v2f xx = __builtin_shufflevector(a,  a,  0, 1);
        v2f yy = __builtin_shufflevector(a,  a,  2, 3);
        v2f zz = __builtin_shufflevector(bz, bz, 0, 1);
        v2f ww = __builtin_shufflevector(bz, bz, 2, 3);
        v2f t = pk_fma(xx, RX, ww);
        t = pk_fma(yy, RY, t);
        t = pk_fma(zz, RZ, t);
        t = pk_add(t, RC);
        accx += fast_exp2(t.x);
        accy += fast_exp2(t.y);
    }
    return accx + accy;
}

// ---------------------------------------------------------------------------
// Dual-batch, fully software-pipelined persistent kernel: no wait(X) is ever
// adjacent to arrive(X) -- the other batch's compute phase sits between, so
// barrier propagation is always hidden.
// LDS = 128 KB tiles + 2.2 KB reduce pad; 1 block/CU, 4 waves/SIMD.
// ---------------------------------------------------------------------------
__global__ __launch_bounds__(THREADS, 4) void sinkhorn_kernel(
        const float* __restrict__ x1, const float* __restrict__ x2,
        float* __restrict__ u, float* __restrict__ v,
        unsigned int* __restrict__ flags, float* __restrict__ out)
{
    __shared__ v4f c1XY[2][NPAIR], c1ZW[2][NPAIR];   // side-1 (dual = u)
    __shared__ v4f c2XY[2][NPAIR], c2ZW[2][NPAIR];   // side-2 (dual = v)
    __shared__ float part[32][17];                   // padded cross-wave reduce

    const int b0   = blockIdx.x / TILES;      // 0..3
    const int tile = blockIdx.x % TILES;
    const int bA = b0, bB = b0 + 4;
    const int baseA = bA * NPT, baseB = bB * NPT;
    const int slotA = bA * TILES + tile, slotB = bB * TILES + tile;
    const unsigned int* flA = flags + bA * TILES;
    const unsigned int* flB = flags + bB * TILES;

    const int tid  = threadIdx.x;
    const int wave = tid >> 6;
    const int lane = tid & 63;
    const int rloc = lane & 31;              // local row 0..31
    const int ch   = lane >> 5;              // column half of this wave's span
    const int row  = tile * 32 + rloc;       // global row in batch
    const int p0   = wave * 64 + ch * 32;    // this lane's pair base

    const float log_mu = logf(1.0f / (float)NPT + EPS_LOG);

    // ---- one-time staging: thread t stages pair t, both batches/sides ----
    float P1a[2], P1b[2], P2a[2], P2b[2];
#pragma unroll
    for (int g = 0; g < 2; g++) {
        int base = g ? baseB : baseA;
        const float* p = x1 + 3 * (base + 2 * tid);
        float ax = p[0], ay = p[1], az = p[2];
        float bx = p[3], by = p[4], bz = p[5];
        float na = fmaf(ax, ax, fmaf(ay, ay, az * az));
        float nb = fmaf(bx, bx, fmaf(by, by, bz * bz));
        P1a[g] = na * NEG100C;  P1b[g] = nb * NEG100C;
        c1XY[g][tid] = (v4f){ax * S200C, bx * S200C, ay * S200C, by * S200C};
        c1ZW[g][tid] = (v4f){az * S200C, bz * S200C, P1a[g], P1b[g]};

        p = x2 + 3 * (base + 2 * tid);
        ax = p[0]; ay = p[1]; az = p[2];
        bx = p[3]; by = p[4]; bz = p[5];
        na = fmaf(ax, ax, fmaf(ay, ay, az * az));
        nb = fmaf(bx, bx, fmaf(by, by, bz * bz));
        P2a[g] = na * NEG100C;  P2b[g] = nb * NEG100C;
        c2XY[g][tid] = (v4f){ax * S200C, bx * S200C, ay * S200C, by * S200C};
        c2ZW[g][tid] = (v4f){az * S200C, bz * S200C, P2a[g], P2b[g]};
    }

    // ---- lane's single-row constants (splatted), both sides/batches ----
    v2f RX1[2], RY1[2], RZ1[2], RC1[2], RX2[2], RY2[2], RZ2[2], RC2[2];
    float rc1s[2];
#pragma unroll
    for (int g = 0; g < 2; g++) {
        int base = g ? baseB : baseA;
        const float* p = x1 + 3 * (base + row);
        float a = p[0], bb = p[1], c = p[2];
        float nn = NEG100C * fmaf(a, a, fmaf(bb, bb, c * c));
        RX1[g] = (v2f){a, a};  RY1[g] = (v2f){bb, bb};
        RZ1[g] = (v2f){c, c};  RC1[g] = (v2f){nn, nn};
        rc1s[g] = nn;
        p = x2 + 3 * (base + row);
        a = p[0]; bb = p[1]; c = p[2];
        nn = NEG100C * fmaf(a, a, fmaf(bb, bb, c * c));
        RX2[g] = (v2f){a, a};  RY2[g] = (v2f){bb, bb};
        RZ2[g] = (v2f){c, c};  RC2[g] = (v2f){nn, nn};
    }
    __syncthreads();

    // ---- helpers ----
    auto reduce_store = [&](float s, float* dst) {
        s += __shfl_xor(s, 32, 64);          // combine column halves
        if (lane < 32) part[rloc][wave] = s;
        __syncthreads();
        if (wave == 0) {
            float t = 0.0f;
#pragma unroll
            for (int w = 0; w < 16; w++) t += part[rloc][w];
            float res = log_mu - __logf(t + EPS_LOG);
            if (lane < 32) gstore(dst, res);          // coalesced 128B
        }
    };
    auto fold_u = [&](int g) {   // fresh u -> side-1 w-slots
        u64t d = gload2(u + (g ? baseB : baseA) + 2 * tid);
        reinterpret_cast<v2f*>(&c1ZW[g][tid])[1] = (v2f){
            fmaf(C_LOG2E, __uint_as_float((unsigned)d), P1a[g]),
            fmaf(C_LOG2E, __uint_as_float((unsigned)(d >> 32)), P1b[g])};
        __syncthreads();
    };
    auto fold_v = [&](int g) {   // fresh v -> side-2 w-slots
        u64t d = gload2(v + (g ? baseB : baseA) + 2 * tid);
        reinterpret_cast<v2f*>(&c2ZW[g][tid])[1] = (v2f){
            fmaf(C_LOG2E, __uint_as_float((unsigned)d), P2a[g]),
            fmaf(C_LOG2E, __uint_as_float((unsigned)(d >> 32)), P2b[g])};
        __syncthreads();
    };
    auto comp_u = [&](int g) {   // u = log_mu - log(K e^v): side-2 tiles
        float s = half_core(c2XY[g], c2ZW[g], p0,
                            RX1[g], RY1[g], RZ1[g], RC1[g]);
        reduce_store(s, u + (g ? baseB : baseA) + row);
    };
    auto comp_v = [&](int g) {   // v = log_nu - log(K^T e^u): side-1 tiles
        float s = half_core(c1XY[g], c1ZW[g], p0,
                            RX2[g], RY2[g], RZ2[g], RC2[g]);
        reduce_store(s, v + (g ? baseB : baseA) + row);
    };

    // ---- software-pipelined 50 iterations ----
    // prologue: iteration 0's u-halves (v=0 -> w=P already staged)
    comp_u(0); bar_arrive(flags, slotA, 1);
    comp_u(1); bar_arrive(flags, slotB, 1);

    for (int it = 0; it < ITERS; it++) {
        const unsigned pu = 2 * it + 1, pv = 2 * it + 2;
        bar_wait(flA, wave, lane, pu);           // uB propagates under vA phase
        fold_u(0);
        comp_v(0); bar_arrive(flags, slotA, pv);
        bar_wait(flB, wave, lane, pu);           // vA propagates under vB phase
        fold_u(1);
        comp_v(1); bar_arrive(flags, slotB, pv);
        bar_wait(flA, wave, lane, pv);           // vB propagates under uA' phase
        fold_v(0);
        if (it < ITERS - 1) { comp_u(0); bar_arrive(flags, slotA, pu + 2); }
        bar_wait(flB, wave, lane, pv);           // uA' propagates into next iter
        fold_v(1);
        if (it < ITERS - 1) { comp_u(1); bar_arrive(flags, slotB, pu + 2); }
    }

    // ---- fused EMD epilogue (both batches):
    //      cost = 0.01*(u_i+v_j) - 0.01*ln2 * t  (algebraically exact)
    // c2ZW already holds final v folded (loop tail); load v again for cvp.
    v2f* cvp0 = reinterpret_cast<v2f*>(c1XY[0]);   // reused, no other reader
    v2f* cvp1 = reinterpret_cast<v2f*>(c1XY[1]);
    {
        u64t dA = gload2(v + baseA + 2 * tid);
        u64t dB = gload2(v + baseB + 2 * tid);
        cvp0[tid] = (v2f){0.01f * __uint_as_float((unsigned)dA),
                          0.01f * __uint_as_float((unsigned)(dA >> 32))};
        cvp1[tid] = (v2f){0.01f * __uint_as_float((unsigned)dB),
                          0.01f * __uint_as_float((unsigned)(dB >> 32))};
    }
    __syncthreads();

    const v2f NL2 = {-LN2_01, -LN2_01};
    float es[2];
#pragma unroll
    for (int g = 0; g < 2; g++) {
        int base = g ? baseB : baseA;
        v2f* cvp = g ? cvp1 : cvp0;
        float ur = gload(&u[base + row]);
        float rcs = fmaf(C_LOG2E, ur, rc1s[g]);
        v2f RCC = (v2f){rcs, rcs};
        float sus = 0.01f * ur;
        v2f SU = (v2f){sus, sus};
        v2f eacc = {0.0f, 0.0f};
#pragma unroll 4
        for (int s = 0; s < 32; s++) {
            v4f a   = c2XY[g][p0 + s];
            v4f bz  = c2ZW[g][p0 + s];
            v2f cv2 = cvp[p0 + s];
            v2f xx = __builtin_shufflevector(a,  a,  0, 1);
            v2f yy = __builtin_shufflevector(a,  a,  2, 3);
            v2f zz = __builtin_shufflevector(bz, bz, 0, 1);
            v2f ww = __builtin_shufflevector(bz, bz, 2, 3);
            v2f t = pk_fma(xx, RX1[g], ww);
            t = pk_fma(yy, RY1[g], t);
            t = pk_fma(zz, RZ1[g], t);
            t = pk_add(t, RCC);
            v2f c2 = pk_fma(t, NL2, pk_add(SU, cv2));
            eacc.x = fmaf(fast_exp2(t.x), c2.x, eacc.x);
            eacc.y = fmaf(fast_exp2(t.y), c2.y, eacc.y);
        }
        float e = eacc.x + eacc.y;
#pragma unroll
        for (int m = 32; m >= 1; m >>= 1) e += __shfl_xor(e, m, 64);
        es[g] = e;
    }

    if (lane == 0) { part[0][wave] = es[0]; part[1][wave] = es[1]; }
    __syncthreads();
    if (tid == 0) {
        float sA = 0.0f, sB = 0.0f;
#pragma unroll
        for (int w = 0; w < 16; w++) { sA += part[0][w]; sB += part[1][w]; }
        atomicAdd(&out[bA], sA);
        atomicAdd(&out[bB], sB);
    }
}

// ---------------------------------------------------------------------------
extern "C" void kernel_launch(void* const* d_in, const int* in_sizes, int n_in,
                              void* d_out, int out_size, void* d_ws, size_t ws_size,
                              hipStream_t stream) {
    (void)in_sizes; (void)n_in; (void)out_size; (void)ws_size;
    const float* x1 = (const float*)d_in[0];
    const float* x2 = (const float*)d_in[1];
    float* out = (float*)d_out;

    char* ws = (char*)d_ws;
    float* u = (float*)ws;                             // NPTS floats
    float* v = u + NPTS;                               // NPTS floats
    unsigned int* flags = (unsigned int*)(v + NPTS);   // BATCH*TILES uints

    init_kernel<<<1, 512, 0, stream>>>(out, flags);
    sinkhorn_kernel<<<GRID_MAIN, THREADS, 0, stream>>>(x1, x2, u, v, flags, out);
}